// Round 9
// baseline (259.165 us; speedup 1.0000x reference)
//
#include <hip/hip_runtime.h>
#include <hip/hip_bf16.h>

// Attn: energies = out_state @ (history @ W.T).T ; softmax rows.
// S2=S1=4096, N=1024. fp32 in/out. bf16 hi/lo GEMM, 3 products
// (Ah.Bh + Al.Bh + Ah.Bl), separate hi/lo arrays (R15: -33% staged bytes).
// R18 post-mortem: 4th failed schedule surgery; slab slot cost is ~7.5-8k cyc
//   INVARIANT to payload (gemm_e 768 MFMA/slab == gemm_p 192 MFMA/slab cost),
//   and 2-blocks/CU co-residency does NOT overlap slots. The game is slab
//   COUNT x payload, not schedule.
// R19: stage-1 gets the stage-2 slab verbatim: 256x256 tile, split-K=4.
//   Grid 256 = 4 K-quarters x 64 tiles, 1 block/CU, 8 slabs/block (was
//   2x16 slab-instances/CU). fp32 partials stored in d_out (64 MB, exactly
//   fits; gemm_e overwrites it later) -> no extra workspace. reduce_split4
//   (80 MB, ~14 us) sums 4 partials -> Ph,Pl. Stage-2 untouched.

typedef __bf16 bf16x8 __attribute__((ext_vector_type(8)));
typedef float f32x4 __attribute__((ext_vector_type(4)));
typedef unsigned short u16x4 __attribute__((ext_vector_type(4)));

__device__ __forceinline__ unsigned short f2bf(float x) {
  unsigned int u = __float_as_uint(x);
  u += 0x7fffu + ((u >> 16) & 1u);   // RNE
  return (unsigned short)(u >> 16);
}
__device__ __forceinline__ float bf2f(unsigned short h) {
  return __uint_as_float(((unsigned int)h) << 16);
}

__device__ __forceinline__ void async_copy_16(void* lds, const void* gsrc) {
  __builtin_amdgcn_global_load_lds(
      (const __attribute__((address_space(1))) void*)gsrc,
      (__attribute__((address_space(3))) void*)lds, 16, 0, 0);
}

__device__ __forceinline__ void barrier_fenced() {
  asm volatile("" ::: "memory");
  __builtin_amdgcn_s_barrier();
  asm volatile("" ::: "memory");
}

// Split fp32 X[rows x 1024] -> Yh, Yl [rows x 1024] bf16 (hi + residual-lo).
__global__ __launch_bounds__(256)
void split_kernel(const float* __restrict__ X, unsigned short* __restrict__ Yh,
                  unsigned short* __restrict__ Yl) {
  const size_t row = blockIdx.x;
  const int c4 = threadIdx.x;
  float4 x = ((const float4*)(X + row * 1024))[c4];
  float xs[4] = {x.x, x.y, x.z, x.w};
  u16x4 h, l;
#pragma unroll
  for (int i = 0; i < 4; ++i) {
    unsigned short hh = f2bf(xs[i]);
    h[i] = hh;
    l[i] = f2bf(xs[i] - bf2f(hh));
  }
  ((u16x4*)(Yh + row * 1024))[c4] = h;
  ((u16x4*)(Yl + row * 1024))[c4] = l;
}

// ============================ stage-2: energies =============================
// C[4096,4096] = Ah.Bh^T + Al.Bh^T + Ah.Bl^T, K=1024. 256x256 tile, 8 waves
// (2x4), wave tile 128x64. NBUF=2, 6-window pipelined slab (R18 body).
// Fragment-ordered LDS: 16-row group g at byte g*1024 + lane*16; matches
// global_load_lds wave-uniform-base + lane*16; 2-way bank alias only.
__global__ __launch_bounds__(512, 2)
void gemm_e(const unsigned short* __restrict__ Ah, const unsigned short* __restrict__ Al,
            const unsigned short* __restrict__ Bh, const unsigned short* __restrict__ Bl,
            float* __restrict__ C) {
  constexpr int MT = 8, NT = 4, NA = 2, NB = 2, NTILES = 32;
  __shared__ unsigned short AhS[2][256 * 32];
  __shared__ unsigned short AlS[2][256 * 32];
  __shared__ unsigned short BhS[2][256 * 32];
  __shared__ unsigned short BlS[2][256 * 32];

  const int tid = threadIdx.x;
  const int w = tid >> 6;
  const int lane = tid & 63;
  const int wm = w >> 2, wn = w & 3;
  const int lr = lane & 15;
  const int ls = lane >> 4;

  // XCD swizzle: grid 256 = 8 XCDs x 32; bijective
  const int id = blockIdx.x;
  const int xcd = id & 7;
  const int j = id >> 3;
  const int bm = ((xcd % 4) * 4 + (j % 4)) * 256;
  const int bn = ((xcd / 4) * 8 + (j / 4)) * 256;

  const unsigned short *pah[NA], *pal[NA];
#pragma unroll
  for (int c = 0; c < NA; ++c) {
    const size_t r = (size_t)(bm + (w * NA + c) * 16 + lr) * 1024 + ls * 8;
    pah[c] = Ah + r; pal[c] = Al + r;
  }
  const unsigned short *pbh[NB], *pbl[NB];
#pragma unroll
  for (int c = 0; c < NB; ++c) {
    const size_t r = (size_t)(bn + (w * NB + c) * 16 + lr) * 1024 + ls * 8;
    pbh[c] = Bh + r; pbl[c] = Bl + r;
  }

  f32x4 acc[MT][NT] = {};

  auto stageAh = [&](int buf, int t) {
#pragma unroll
    for (int c = 0; c < NA; ++c)
      async_copy_16(&AhS[buf][(w * NA + c) * 512], pah[c] + t * 32);
  };
  auto stageAl = [&](int buf, int t) {
#pragma unroll
    for (int c = 0; c < NA; ++c)
      async_copy_16(&AlS[buf][(w * NA + c) * 512], pal[c] + t * 32);
  };
  auto stageBh = [&](int buf, int t) {
#pragma unroll
    for (int c = 0; c < NB; ++c)
      async_copy_16(&BhS[buf][(w * NB + c) * 512], pbh[c] + t * 32);
  };
  auto stageBl = [&](int buf, int t) {
#pragma unroll
    for (int c = 0; c < NB; ++c)
      async_copy_16(&BlS[buf][(w * NB + c) * 512], pbl[c] + t * 32);
  };
  auto LDAh = [&](int buf, int g) { return *(const bf16x8*)&AhS[buf][g * 512 + ls * 128 + lr * 8]; };
  auto LDAl = [&](int buf, int g) { return *(const bf16x8*)&AlS[buf][g * 512 + ls * 128 + lr * 8]; };
  auto LDBh = [&](int buf, int g) { return *(const bf16x8*)&BhS[buf][g * 512 + ls * 128 + lr * 8]; };
  auto LDBl = [&](int buf, int g) { return *(const bf16x8*)&BlS[buf][g * 512 + ls * 128 + lr * 8]; };

  stageAh(0, 0); stageAl(0, 0); stageBh(0, 0); stageBl(0, 0);
  asm volatile("s_waitcnt vmcnt(0)" ::: "memory");
  barrier_fenced();

#pragma unroll 1
  for (int t = 0; t < NTILES; ++t) {
    const int buf = t & 1, nb = buf ^ 1;
    const bool st = (t + 1 < NTILES);
    bf16x8 ah[8], al[8], bh[4], bl[4];

    // w0 (refill): read ah[0..4)+bh; issue Ah(t+1)
#pragma unroll
    for (int mt = 0; mt < 4; ++mt) ah[mt] = LDAh(buf, wm * MT + mt);
#pragma unroll
    for (int nt = 0; nt < 4; ++nt) bh[nt] = LDBh(buf, wn * NT + nt);
    if (st) stageAh(nb, t + 1);
    barrier_fenced();

    // w1: read ah[4..8) (for w2); issue Bh(t+1); MFMA ah[0..4) x bh
#pragma unroll
    for (int mt = 4; mt < 8; ++mt) ah[mt] = LDAh(buf, wm * MT + mt);
    if (st) stageBh(nb, t + 1);
    __builtin_amdgcn_s_setprio(1);
#pragma unroll
    for (int mt = 0; mt < 4; ++mt)
#pragma unroll
      for (int nt = 0; nt < 4; ++nt)
        acc[mt][nt] = __builtin_amdgcn_mfma_f32_16x16x32_bf16(ah[mt], bh[nt], acc[mt][nt], 0, 0, 0);
    __builtin_amdgcn_s_setprio(0);
    barrier_fenced();

    // w2: read bl (for w3); issue Al(t+1); MFMA ah[4..8) x bh
#pragma unroll
    for (int nt = 0; nt < 4; ++nt) bl[nt] = LDBl(buf, wn * NT + nt);
    if (st) stageAl(nb, t + 1);
    __builtin_amdgcn_s_setprio(1);
#pragma unroll
    for (int mt = 4; mt < 8; ++mt)
#pragma unroll
      for (int nt = 0; nt < 4; ++nt)
        acc[mt][nt] = __builtin_amdgcn_mfma_f32_16x16x32_bf16(ah[mt], bh[nt], acc[mt][nt], 0, 0, 0);
    __builtin_amdgcn_s_setprio(0);
    barrier_fenced();

    // w3: read al[0..4) (for w5); issue Bl(t+1); MFMA ah[0..4) x bl
#pragma unroll
    for (int mt = 0; mt < 4; ++mt) al[mt] = LDAl(buf, wm * MT + mt);
    if (st) stageBl(nb, t + 1);
    __builtin_amdgcn_s_setprio(1);
#pragma unroll
    for (int mt = 0; mt < 4; ++mt)
#pragma unroll
      for (int nt = 0; nt < 4; ++nt)
        acc[mt][nt] = __builtin_amdgcn_mfma_f32_16x16x32_bf16(ah[mt], bl[nt], acc[mt][nt], 0, 0, 0);
    __builtin_amdgcn_s_setprio(0);
    barrier_fenced();

    // w4: read al[4..8); MFMA ah[4..8) x bl
#pragma unroll
    for (int mt = 4; mt < 8; ++mt) al[mt] = LDAl(buf, wm * MT + mt);
    __builtin_amdgcn_s_setprio(1);
#pragma unroll
    for (int mt = 4; mt < 8; ++mt)
#pragma unroll
      for (int nt = 0; nt < 4; ++nt)
        acc[mt][nt] = __builtin_amdgcn_mfma_f32_16x16x32_bf16(ah[mt], bl[nt], acc[mt][nt], 0, 0, 0);
    __builtin_amdgcn_s_setprio(0);
    barrier_fenced();

    // w5: MFMA al x bh (32)
    __builtin_amdgcn_s_setprio(1);
#pragma unroll
    for (int mt = 0; mt < 8; ++mt)
#pragma unroll
      for (int nt = 0; nt < 4; ++nt)
        acc[mt][nt] = __builtin_amdgcn_mfma_f32_16x16x32_bf16(al[mt], bh[nt], acc[mt][nt], 0, 0, 0);
    __builtin_amdgcn_s_setprio(0);

    // boundary: drain slab t+1's DMAs + our reads of buf (recycled next)
    __builtin_amdgcn_sched_barrier(0);
    asm volatile("s_waitcnt vmcnt(0) lgkmcnt(0)" ::: "memory");
    barrier_fenced();
  }

  // Epilogue. C/D layout: col = lane&15, row = (lane>>4)*4 + reg.
  const int cm0 = bm + wm * 128;
  const int cn0 = bn + wn * 64;
#pragma unroll
  for (int mt = 0; mt < MT; ++mt)
#pragma unroll
    for (int nt = 0; nt < NT; ++nt) {
      const int col = cn0 + nt * 16 + lr;
      const int row0 = cm0 + mt * 16 + ls * 4;
#pragma unroll
      for (int r = 0; r < 4; ++r)
        C[(size_t)(row0 + r) * 4096 + col] = acc[mt][nt][r];
    }
}

// ====================== stage-1: proj (split-K=4, 256x256) ==================
// Cpart[kq][4096,1024] = partial over K-quarter kq of Ah.Bh + Al.Bh + Ah.Bl.
// IDENTICAL slab body to gemm_e; 8 slabs/block; grid 256 = 4 kq x 64 tiles
// (16 bm x 4 bn), 1 block/CU. Partials land in d_out (scratch reuse).
__global__ __launch_bounds__(512, 2)
void gemm_p(const unsigned short* __restrict__ Ah, const unsigned short* __restrict__ Al,
            const unsigned short* __restrict__ Bh, const unsigned short* __restrict__ Bl,
            float* __restrict__ Cpart) {
  constexpr int MT = 8, NT = 4, NA = 2, NB = 2, NTILES = 8;
  __shared__ unsigned short AhS[2][256 * 32];
  __shared__ unsigned short AlS[2][256 * 32];
  __shared__ unsigned short BhS[2][256 * 32];
  __shared__ unsigned short BlS[2][256 * 32];

  const int tid = threadIdx.x;
  const int w = tid >> 6;
  const int lane = tid & 63;
  const int wm = w >> 2, wn = w & 3;
  const int lr = lane & 15;
  const int ls = lane >> 4;

  // grid 256 = 4 K-quarters x 64 tiles; tile part XCD-spread (bijective)
  const int id = blockIdx.x;
  const int kq = id >> 6;
  const int id6 = id & 63;
  const int xcd = id6 & 7;
  const int j = id6 >> 3;
  const int bm = ((xcd & 3) * 4 + (j & 3)) * 256;   // 16 values
  const int bn = ((xcd >> 2) * 2 + (j >> 2)) * 256; // 4 values
  const int koff = kq * 256;
  float* __restrict__ C = Cpart + (size_t)kq * 4096 * 1024;

  const unsigned short *pah[NA], *pal[NA];
#pragma unroll
  for (int c = 0; c < NA; ++c) {
    const size_t r = (size_t)(bm + (w * NA + c) * 16 + lr) * 1024 + koff + ls * 8;
    pah[c] = Ah + r; pal[c] = Al + r;
  }
  const unsigned short *pbh[NB], *pbl[NB];
#pragma unroll
  for (int c = 0; c < NB; ++c) {
    const size_t r = (size_t)(bn + (w * NB + c) * 16 + lr) * 1024 + koff + ls * 8;
    pbh[c] = Bh + r; pbl[c] = Bl + r;
  }

  f32x4 acc[MT][NT] = {};

  auto stageAh = [&](int buf, int t) {
#pragma unroll
    for (int c = 0; c < NA; ++c)
      async_copy_16(&AhS[buf][(w * NA + c) * 512], pah[c] + t * 32);
  };
  auto stageAl = [&](int buf, int t) {
#pragma unroll
    for (int c = 0; c < NA; ++c)
      async_copy_16(&AlS[buf][(w * NA + c) * 512], pal[c] + t * 32);
  };
  auto stageBh = [&](int buf, int t) {
#pragma unroll
    for (int c = 0; c < NB; ++c)
      async_copy_16(&BhS[buf][(w * NB + c) * 512], pbh[c] + t * 32);
  };
  auto stageBl = [&](int buf, int t) {
#pragma unroll
    for (int c = 0; c < NB; ++c)
      async_copy_16(&BlS[buf][(w * NB + c) * 512], pbl[c] + t * 32);
  };
  auto LDAh = [&](int buf, int g) { return *(const bf16x8*)&AhS[buf][g * 512 + ls * 128 + lr * 8]; };
  auto LDAl = [&](int buf, int g) { return *(const bf16x8*)&AlS[buf][g * 512 + ls * 128 + lr * 8]; };
  auto LDBh = [&](int buf, int g) { return *(const bf16x8*)&BhS[buf][g * 512 + ls * 128 + lr * 8]; };
  auto LDBl = [&](int buf, int g) { return *(const bf16x8*)&BlS[buf][g * 512 + ls * 128 + lr * 8]; };

  stageAh(0, 0); stageAl(0, 0); stageBh(0, 0); stageBl(0, 0);
  asm volatile("s_waitcnt vmcnt(0)" ::: "memory");
  barrier_fenced();

#pragma unroll 1
  for (int t = 0; t < NTILES; ++t) {
    const int buf = t & 1, nb = buf ^ 1;
    const bool st = (t + 1 < NTILES);
    bf16x8 ah[8], al[8], bh[4], bl[4];

    // w0 (refill): read ah[0..4)+bh; issue Ah(t+1)
#pragma unroll
    for (int mt = 0; mt < 4; ++mt) ah[mt] = LDAh(buf, wm * MT + mt);
#pragma unroll
    for (int nt = 0; nt < 4; ++nt) bh[nt] = LDBh(buf, wn * NT + nt);
    if (st) stageAh(nb, t + 1);
    barrier_fenced();

    // w1: read ah[4..8); issue Bh(t+1); MFMA ah[0..4) x bh
#pragma unroll
    for (int mt = 4; mt < 8; ++mt) ah[mt] = LDAh(buf, wm * MT + mt);
    if (st) stageBh(nb, t + 1);
    __builtin_amdgcn_s_setprio(1);
#pragma unroll
    for (int mt = 0; mt < 4; ++mt)
#pragma unroll
      for (int nt = 0; nt < 4; ++nt)
        acc[mt][nt] = __builtin_amdgcn_mfma_f32_16x16x32_bf16(ah[mt], bh[nt], acc[mt][nt], 0, 0, 0);
    __builtin_amdgcn_s_setprio(0);
    barrier_fenced();

    // w2: read bl; issue Al(t+1); MFMA ah[4..8) x bh
#pragma unroll
    for (int nt = 0; nt < 4; ++nt) bl[nt] = LDBl(buf, wn * NT + nt);
    if (st) stageAl(nb, t + 1);
    __builtin_amdgcn_s_setprio(1);
#pragma unroll
    for (int mt = 4; mt < 8; ++mt)
#pragma unroll
      for (int nt = 0; nt < 4; ++nt)
        acc[mt][nt] = __builtin_amdgcn_mfma_f32_16x16x32_bf16(ah[mt], bh[nt], acc[mt][nt], 0, 0, 0);
    __builtin_amdgcn_s_setprio(0);
    barrier_fenced();

    // w3: read al[0..4); issue Bl(t+1); MFMA ah[0..4) x bl
#pragma unroll
    for (int mt = 0; mt < 4; ++mt) al[mt] = LDAl(buf, wm * MT + mt);
    if (st) stageBl(nb, t + 1);
    __builtin_amdgcn_s_setprio(1);
#pragma unroll
    for (int mt = 0; mt < 4; ++mt)
#pragma unroll
      for (int nt = 0; nt < 4; ++nt)
        acc[mt][nt] = __builtin_amdgcn_mfma_f32_16x16x32_bf16(ah[mt], bl[nt], acc[mt][nt], 0, 0, 0);
    __builtin_amdgcn_s_setprio(0);
    barrier_fenced();

    // w4: read al[4..8); MFMA ah[4..8) x bl
#pragma unroll
    for (int mt = 4; mt < 8; ++mt) al[mt] = LDAl(buf, wm * MT + mt);
    __builtin_amdgcn_s_setprio(1);
#pragma unroll
    for (int mt = 4; mt < 8; ++mt)
#pragma unroll
      for (int nt = 0; nt < 4; ++nt)
        acc[mt][nt] = __builtin_amdgcn_mfma_f32_16x16x32_bf16(ah[mt], bl[nt], acc[mt][nt], 0, 0, 0);
    __builtin_amdgcn_s_setprio(0);
    barrier_fenced();

    // w5: MFMA al x bh (32)
    __builtin_amdgcn_s_setprio(1);
#pragma unroll
    for (int mt = 0; mt < 8; ++mt)
#pragma unroll
      for (int nt = 0; nt < 4; ++nt)
        acc[mt][nt] = __builtin_amdgcn_mfma_f32_16x16x32_bf16(al[mt], bh[nt], acc[mt][nt], 0, 0, 0);
    __builtin_amdgcn_s_setprio(0);

    // boundary
    __builtin_amdgcn_sched_barrier(0);
    asm volatile("s_waitcnt vmcnt(0) lgkmcnt(0)" ::: "memory");
    barrier_fenced();
  }

  // Epilogue: fp32 partial write into Cpart[kq].
  const int cm0 = bm + wm * 128;
  const int cn0 = bn + wn * 64;
#pragma unroll
  for (int mt = 0; mt < MT; ++mt)
#pragma unroll
    for (int nt = 0; nt < NT; ++nt) {
      const int col = cn0 + nt * 16 + lr;
      const int row0 = cm0 + mt * 16 + ls * 4;
#pragma unroll
      for (int r = 0; r < 4; ++r)
        C[(size_t)(row0 + r) * 1024 + col] = acc[mt][nt][r];
    }
}

// P = P0+P1+P2+P3; split hi/lo into Ph, Pl. Row per block.
__global__ __launch_bounds__(256)
void reduce_split4(const float* __restrict__ P, unsigned short* __restrict__ Ph,
                   unsigned short* __restrict__ Pl) {
  const size_t row = blockIdx.x;
  const int c4 = threadIdx.x;
  constexpr size_t STRIDE = (size_t)4096 * 1024;
  float4 a0 = ((const float4*)(P + row * 1024))[c4];
  float4 a1 = ((const float4*)(P + STRIDE + row * 1024))[c4];
  float4 a2 = ((const float4*)(P + 2 * STRIDE + row * 1024))[c4];
  float4 a3 = ((const float4*)(P + 3 * STRIDE + row * 1024))[c4];
  float s[4] = {(a0.x + a1.x) + (a2.x + a3.x), (a0.y + a1.y) + (a2.y + a3.y),
                (a0.z + a1.z) + (a2.z + a3.z), (a0.w + a1.w) + (a2.w + a3.w)};
  u16x4 h, l;
#pragma unroll
  for (int i = 0; i < 4; ++i) {
    unsigned short hh = f2bf(s[i]);
    h[i] = hh;
    l[i] = f2bf(s[i] - bf2f(hh));
  }
  ((u16x4*)(Ph + row * 1024))[c4] = h;
  ((u16x4*)(Pl + row * 1024))[c4] = l;
}

// In-place row softmax, N=4096, one block per row, 16 floats/thread in regs.
__global__ __launch_bounds__(256)
void softmax_inplace(float* __restrict__ C, int N) {
  float4* r4 = (float4*)(C + (size_t)blockIdx.x * N);
  const int t = threadIdx.x;
  float4 v[4];
  float mx = -3.0e38f;
#pragma unroll
  for (int i = 0; i < 4; ++i) {
    v[i] = r4[t + i * 256];
    mx = fmaxf(mx, fmaxf(fmaxf(v[i].x, v[i].y), fmaxf(v[i].z, v[i].w)));
  }
#pragma unroll
  for (int o = 32; o; o >>= 1) mx = fmaxf(mx, __shfl_xor(mx, o, 64));
  __shared__ float smax[4], ssum[4];
  const int w = t >> 6;
  if ((t & 63) == 0) smax[w] = mx;
  __syncthreads();
  mx = fmaxf(fmaxf(smax[0], smax[1]), fmaxf(smax[2], smax[3]));
  float s = 0.f;
#pragma unroll
  for (int i = 0; i < 4; ++i) {
    v[i].x = __expf(v[i].x - mx);
    v[i].y = __expf(v[i].y - mx);
    v[i].z = __expf(v[i].z - mx);
    v[i].w = __expf(v[i].w - mx);
    s += (v[i].x + v[i].y) + (v[i].z + v[i].w);
  }
#pragma unroll
  for (int o = 32; o; o >>= 1) s += __shfl_xor(s, o, 64);
  if ((t & 63) == 0) ssum[w] = s;
  __syncthreads();
  const float inv = 1.0f / (ssum[0] + ssum[1] + ssum[2] + ssum[3]);
#pragma unroll
  for (int i = 0; i < 4; ++i) {
    v[i].x *= inv; v[i].y *= inv; v[i].z *= inv; v[i].w *= inv;
    r4[t + i * 256] = v[i];
  }
}

extern "C" void kernel_launch(void* const* d_in, const int* in_sizes, int n_in,
                              void* d_out, int out_size, void* d_ws, size_t ws_size,
                              hipStream_t stream) {
  const float* out_state = (const float*)d_in[0];  // [4096,1024]
  const float* history   = (const float*)d_in[1];  // [4096,1024]
  const float* W         = (const float*)d_in[2];  // [1024,1024]
  float* out = (float*)d_out;                      // [4096,4096]

  unsigned short* Hh = (unsigned short*)d_ws;                 // 4096x1024 each
  unsigned short* Hl = Hh + (size_t)4096 * 1024;
  unsigned short* Wh = Hl + (size_t)4096 * 1024;              // 1024x1024
  unsigned short* Wl = Wh + (size_t)1024 * 1024;
  unsigned short* Ah = Wl + (size_t)1024 * 1024;              // 4096x1024
  unsigned short* Al = Ah + (size_t)4096 * 1024;
  unsigned short* Ph = Al + (size_t)4096 * 1024;              // 4096x1024
  unsigned short* Pl = Ph + (size_t)4096 * 1024;

  // d_out (64 MB) doubles as the 4 x [4096,1024] fp32 partial scratch for
  // stage-1; reduce_split4 consumes it before gemm_e overwrites it.
  float* P32 = out;

  split_kernel<<<4096, 256, 0, stream>>>(history, Hh, Hl);
  split_kernel<<<1024, 256, 0, stream>>>(W, Wh, Wl);
  split_kernel<<<4096, 256, 0, stream>>>(out_state, Ah, Al);

  // stage-1: split-K=4 proj with the stage-2 slab. 256 blocks, 1 block/CU,
  // 8 slabs/block.
  gemm_p<<<256, 512, 0, stream>>>(Hh, Hl, Wh, Wl, P32);
  reduce_split4<<<4096, 256, 0, stream>>>(P32, Ph, Pl);

  // stage-2: energies. 6-window pipelined slab (R18 body), 256 blocks.
  gemm_e<<<256, 512, 0, stream>>>(Ah, Al, Ph, Pl, out);

  softmax_inplace<<<4096, 256, 0, stream>>>(out, 4096);
}

// Round 10
// 252.975 us; speedup vs baseline: 1.0245x; 1.0245x over previous
//
#include <hip/hip_runtime.h>
#include <hip/hip_bf16.h>

// Attn: energies = out_state @ (history @ W.T).T ; softmax rows.
// S2=S1=4096, N=1024. fp32 in/out. bf16 hi/lo GEMM, 3 products
// (Ah.Bh + Al.Bh + Ah.Bl), separate hi/lo arrays (R15: -33% staged bytes).
// R19 post-mortem: gemm_p with gemm_e's IDENTICAL slab body (8 slabs) still
//   ~100 us (29k cyc/slab vs gemm_e's 8k) -- stage-1 invariant across 7
//   structures; need counters (hidden below top-5 cutoff).
// R20: (1) gemm_e -> mfma_f32_32x32x16_bf16: half the MFMA insts, ~17%
//   better FLOP/cyc (m119: 8.07 cyc/32k vs 4.85/16k), same bytes/banks.
//   A-layout row=lane&31, k=(lane>>5)*8+j (M=16 version m89-verified);
//   C/D: col=lane&31, row=(reg&3)+8*(reg>>2)+4*(lane>>5) (m74/m101).
//   (2) gemm_e dropping below gemm_p should surface gemm_p in top-5 WITH
//   counters. (3) splits fused into one kernel. gemm_p/reduce = R17-exact.

typedef __bf16 bf16x8 __attribute__((ext_vector_type(8)));
typedef float f32x4 __attribute__((ext_vector_type(4)));
typedef float f32x16 __attribute__((ext_vector_type(16)));
typedef unsigned short u16x4 __attribute__((ext_vector_type(4)));

__device__ __forceinline__ unsigned short f2bf(float x) {
  unsigned int u = __float_as_uint(x);
  u += 0x7fffu + ((u >> 16) & 1u);   // RNE
  return (unsigned short)(u >> 16);
}
__device__ __forceinline__ float bf2f(unsigned short h) {
  return __uint_as_float(((unsigned int)h) << 16);
}

__device__ __forceinline__ void async_copy_16(void* lds, const void* gsrc) {
  __builtin_amdgcn_global_load_lds(
      (const __attribute__((address_space(1))) void*)gsrc,
      (__attribute__((address_space(3))) void*)lds, 16, 0, 0);
}

__device__ __forceinline__ void barrier_fenced() {
  asm volatile("" ::: "memory");
  __builtin_amdgcn_s_barrier();
  asm volatile("" ::: "memory");
}

// Fused split: fp32 X[rows x 1024] -> Yh, Yl bf16 (hi + residual-lo) for
// history (4096), W (1024), out_state (4096) in one launch (grid 9216).
__global__ __launch_bounds__(256)
void split_all(const float* __restrict__ H, const float* __restrict__ W,
               const float* __restrict__ OS,
               unsigned short* __restrict__ Hh, unsigned short* __restrict__ Hl,
               unsigned short* __restrict__ Wh, unsigned short* __restrict__ Wl,
               unsigned short* __restrict__ Ah, unsigned short* __restrict__ Al) {
  const int b = blockIdx.x;
  const float* X; unsigned short *Yh, *Yl; size_t row;
  if (b < 4096)      { X = H;  Yh = Hh; Yl = Hl; row = b; }
  else if (b < 5120) { X = W;  Yh = Wh; Yl = Wl; row = b - 4096; }
  else               { X = OS; Yh = Ah; Yl = Al; row = b - 5120; }
  const int c4 = threadIdx.x;
  float4 x = ((const float4*)(X + row * 1024))[c4];
  float xs[4] = {x.x, x.y, x.z, x.w};
  u16x4 h, l;
#pragma unroll
  for (int i = 0; i < 4; ++i) {
    unsigned short hh = f2bf(xs[i]);
    h[i] = hh;
    l[i] = f2bf(xs[i] - bf2f(hh));
  }
  ((u16x4*)(Yh + row * 1024))[c4] = h;
  ((u16x4*)(Yl + row * 1024))[c4] = l;
}

// ===================== stage-2: energies (32x32x16 MFMA) ====================
// C[4096,4096] = Ah.Bh^T + Al.Bh^T + Ah.Bl^T, K=1024. 256x256 tile, 8 waves
// (2x4), wave tile 128x64 = 4x2 frags of 32x32. Per K=32 slab: 2 k-steps
// (h=0,1) of K=16. LDS per array per slab: 8 groups x [h:2][kseg:2][row:32]
// [8 bf16] = 2 KB/group; all reads/DMA-dests are base + lane*16.
__global__ __launch_bounds__(512, 2)
void gemm_e(const unsigned short* __restrict__ Ah, const unsigned short* __restrict__ Al,
            const unsigned short* __restrict__ Bh, const unsigned short* __restrict__ Bl,
            float* __restrict__ C) {
  constexpr int NTILES = 32;
  __shared__ unsigned short AhS[2][256 * 32];
  __shared__ unsigned short AlS[2][256 * 32];
  __shared__ unsigned short BhS[2][256 * 32];
  __shared__ unsigned short BlS[2][256 * 32];

  const int tid = threadIdx.x;
  const int w = tid >> 6;
  const int lane = tid & 63;
  const int wm = w >> 2, wn = w & 3;
  const int lr = lane & 31;              // row within 32-group
  const int ls = lane >> 5;              // k-segment (8 bf16)

  // XCD swizzle: grid 256 = 8 XCDs x 32; bijective
  const int id = blockIdx.x;
  const int xcd = id & 7;
  const int j = id >> 3;
  const int bm = ((xcd % 4) * 4 + (j % 4)) * 256;
  const int bn = ((xcd / 4) * 8 + (j / 4)) * 256;

  // staging source pointers: wave w owns 32-row group w on each side.
  const unsigned short *pah, *pal, *pbh, *pbl;
  {
    const size_t ra = (size_t)(bm + w * 32 + lr) * 1024 + ls * 8;
    pah = Ah + ra; pal = Al + ra;
    const size_t rb = (size_t)(bn + w * 32 + lr) * 1024 + ls * 8;
    pbh = Bh + rb; pbl = Bl + rb;
  }

  f32x16 acc[4][2] = {};

  // stage array X slab t into buf: 2 DMAs (h=0,1); dest uniform + lane*16.
  auto stageAh = [&](int buf, int t) {
#pragma unroll
    for (int h = 0; h < 2; ++h)
      async_copy_16(&AhS[buf][w * 1024 + h * 512], pah + t * 32 + h * 16);
  };
  auto stageAl = [&](int buf, int t) {
#pragma unroll
    for (int h = 0; h < 2; ++h)
      async_copy_16(&AlS[buf][w * 1024 + h * 512], pal + t * 32 + h * 16);
  };
  auto stageBh = [&](int buf, int t) {
#pragma unroll
    for (int h = 0; h < 2; ++h)
      async_copy_16(&BhS[buf][w * 1024 + h * 512], pbh + t * 32 + h * 16);
  };
  auto stageBl = [&](int buf, int t) {
#pragma unroll
    for (int h = 0; h < 2; ++h)
      async_copy_16(&BlS[buf][w * 1024 + h * 512], pbl + t * 32 + h * 16);
  };
  // fragment read: group g, k-step h; lane holds (row=lane&31, k=h*16+ls*8..)
  auto LDAh = [&](int buf, int g, int h) { return *(const bf16x8*)&AhS[buf][g * 1024 + h * 512 + lane * 8]; };
  auto LDAl = [&](int buf, int g, int h) { return *(const bf16x8*)&AlS[buf][g * 1024 + h * 512 + lane * 8]; };
  auto LDBh = [&](int buf, int g, int h) { return *(const bf16x8*)&BhS[buf][g * 1024 + h * 512 + lane * 8]; };
  auto LDBl = [&](int buf, int g, int h) { return *(const bf16x8*)&BlS[buf][g * 1024 + h * 512 + lane * 8]; };

  stageAh(0, 0); stageAl(0, 0); stageBh(0, 0); stageBl(0, 0);
  asm volatile("s_waitcnt vmcnt(0)" ::: "memory");
  barrier_fenced();

#pragma unroll 1
  for (int t = 0; t < NTILES; ++t) {
    const int buf = t & 1, nb = buf ^ 1;
    const bool st = (t + 1 < NTILES);
    bf16x8 ah[4][2], al[4][2], bh[2][2], bl[2][2];

    // w0 (refill): read ah[0..2) + bh (8 reads); issue Ah(t+1)
#pragma unroll
    for (int mt = 0; mt < 2; ++mt)
#pragma unroll
      for (int h = 0; h < 2; ++h) ah[mt][h] = LDAh(buf, wm * 4 + mt, h);
#pragma unroll
    for (int nt = 0; nt < 2; ++nt)
#pragma unroll
      for (int h = 0; h < 2; ++h) bh[nt][h] = LDBh(buf, wn * 2 + nt, h);
    if (st) stageAh(nb, t + 1);
    barrier_fenced();

    // w1: read ah[2..4); issue Bh(t+1); MFMA ah[0..2) x bh (8)
#pragma unroll
    for (int mt = 2; mt < 4; ++mt)
#pragma unroll
      for (int h = 0; h < 2; ++h) ah[mt][h] = LDAh(buf, wm * 4 + mt, h);
    if (st) stageBh(nb, t + 1);
    __builtin_amdgcn_s_setprio(1);
#pragma unroll
    for (int h = 0; h < 2; ++h)
#pragma unroll
      for (int mt = 0; mt < 2; ++mt)
#pragma unroll
        for (int nt = 0; nt < 2; ++nt)
          acc[mt][nt] = __builtin_amdgcn_mfma_f32_32x32x16_bf16(ah[mt][h], bh[nt][h], acc[mt][nt], 0, 0, 0);
    __builtin_amdgcn_s_setprio(0);
    barrier_fenced();

    // w2: read bl; issue Al(t+1); MFMA ah[2..4) x bh (8)
#pragma unroll
    for (int nt = 0; nt < 2; ++nt)
#pragma unroll
      for (int h = 0; h < 2; ++h) bl[nt][h] = LDBl(buf, wn * 2 + nt, h);
    if (st) stageAl(nb, t + 1);
    __builtin_amdgcn_s_setprio(1);
#pragma unroll
    for (int h = 0; h < 2; ++h)
#pragma unroll
      for (int mt = 2; mt < 4; ++mt)
#pragma unroll
        for (int nt = 0; nt < 2; ++nt)
          acc[mt][nt] = __builtin_amdgcn_mfma_f32_32x32x16_bf16(ah[mt][h], bh[nt][h], acc[mt][nt], 0, 0, 0);
    __builtin_amdgcn_s_setprio(0);
    barrier_fenced();

    // w3: read al[0..2); issue Bl(t+1); MFMA ah[0..2) x bl (8)
#pragma unroll
    for (int mt = 0; mt < 2; ++mt)
#pragma unroll
      for (int h = 0; h < 2; ++h) al[mt][h] = LDAl(buf, wm * 4 + mt, h);
    if (st) stageBl(nb, t + 1);
    __builtin_amdgcn_s_setprio(1);
#pragma unroll
    for (int h = 0; h < 2; ++h)
#pragma unroll
      for (int mt = 0; mt < 2; ++mt)
#pragma unroll
        for (int nt = 0; nt < 2; ++nt)
          acc[mt][nt] = __builtin_amdgcn_mfma_f32_32x32x16_bf16(ah[mt][h], bl[nt][h], acc[mt][nt], 0, 0, 0);
    __builtin_amdgcn_s_setprio(0);
    barrier_fenced();

    // w4: read al[2..4); MFMA ah[2..4) x bl (8)
#pragma unroll
    for (int mt = 2; mt < 4; ++mt)
#pragma unroll
      for (int h = 0; h < 2; ++h) al[mt][h] = LDAl(buf, wm * 4 + mt, h);
    __builtin_amdgcn_s_setprio(1);
#pragma unroll
    for (int h = 0; h < 2; ++h)
#pragma unroll
      for (int mt = 2; mt < 4; ++mt)
#pragma unroll
        for (int nt = 0; nt < 2; ++nt)
          acc[mt][nt] = __builtin_amdgcn_mfma_f32_32x32x16_bf16(ah[mt][h], bl[nt][h], acc[mt][nt], 0, 0, 0);
    __builtin_amdgcn_s_setprio(0);
    barrier_fenced();

    // w5: MFMA al x bh (16)
    __builtin_amdgcn_s_setprio(1);
#pragma unroll
    for (int h = 0; h < 2; ++h)
#pragma unroll
      for (int mt = 0; mt < 4; ++mt)
#pragma unroll
        for (int nt = 0; nt < 2; ++nt)
          acc[mt][nt] = __builtin_amdgcn_mfma_f32_32x32x16_bf16(al[mt][h], bh[nt][h], acc[mt][nt], 0, 0, 0);
    __builtin_amdgcn_s_setprio(0);

    // boundary: drain slab t+1's DMAs + our reads of buf (recycled next)
    __builtin_amdgcn_sched_barrier(0);
    asm volatile("s_waitcnt vmcnt(0) lgkmcnt(0)" ::: "memory");
    barrier_fenced();
  }

  // Epilogue. 32x32 C/D: col = lane&31, row = (reg&3)+8*(reg>>2)+4*(lane>>5).
  const int cm0 = bm + wm * 128;
  const int cn0 = bn + wn * 64;
#pragma unroll
  for (int mt = 0; mt < 4; ++mt)
#pragma unroll
    for (int nt = 0; nt < 2; ++nt) {
      const int col = cn0 + nt * 32 + lr;
      const int row0 = cm0 + mt * 32 + ls * 4;
#pragma unroll
      for (int reg = 0; reg < 16; ++reg) {
        const int row = row0 + (reg & 3) + 8 * (reg >> 2);
        C[(size_t)row * 4096 + col] = acc[mt][nt][reg];
      }
    }
}

// ==================== stage-1: proj (R17-exact, split-K=2) ==================
// Cpart[kh][4096,1024]. 128x128 tile, 8 waves (2x4), wave tile 64x32.
// NBUF=2 -> 64 KB -> 2 blocks/CU. 16 slabs, 3 lockstep windows.
__global__ __launch_bounds__(512, 2)
void gemm_p(const unsigned short* __restrict__ Ah, const unsigned short* __restrict__ Al,
            const unsigned short* __restrict__ Bh, const unsigned short* __restrict__ Bl,
            float* __restrict__ Cpart) {
  constexpr int MT = 4, NT = 2, NTILES = 16;
  __shared__ unsigned short AhS[2][128 * 32];
  __shared__ unsigned short AlS[2][128 * 32];
  __shared__ unsigned short BhS[2][128 * 32];
  __shared__ unsigned short BlS[2][128 * 32];

  const int tid = threadIdx.x;
  const int w = tid >> 6;
  const int lane = tid & 63;
  const int wm = w >> 2, wn = w & 3;
  const int lr = lane & 15;
  const int ls = lane >> 4;

  const int kh = blockIdx.x >> 8;
  const int rid = blockIdx.x & 255;
  const int xcd = rid & 7;
  const int j = rid >> 3;
  const int bm = ((xcd % 4) * 8 + (j % 8)) * 128;
  const int bn = ((xcd / 4) * 4 + (j / 8)) * 128;
  const int koff = kh * 512;
  float* __restrict__ C = Cpart + (size_t)kh * 4096 * 1024;

  const unsigned short *pah, *pal, *pbh, *pbl;
  {
    const size_t ra = (size_t)(bm + w * 16 + lr) * 1024 + koff + ls * 8;
    pah = Ah + ra; pal = Al + ra;
    const size_t rb = (size_t)(bn + w * 16 + lr) * 1024 + koff + ls * 8;
    pbh = Bh + rb; pbl = Bl + rb;
  }

  f32x4 acc[MT][NT] = {};

  auto stage_all = [&](int buf, int t) {
    async_copy_16(&AhS[buf][w * 512], pah + t * 32);
    async_copy_16(&BhS[buf][w * 512], pbh + t * 32);
    async_copy_16(&BlS[buf][w * 512], pbl + t * 32);
    async_copy_16(&AlS[buf][w * 512], pal + t * 32);
  };
  auto LDAh = [&](int buf, int g) { return *(const bf16x8*)&AhS[buf][g * 512 + ls * 128 + lr * 8]; };
  auto LDAl = [&](int buf, int g) { return *(const bf16x8*)&AlS[buf][g * 512 + ls * 128 + lr * 8]; };
  auto LDBh = [&](int buf, int g) { return *(const bf16x8*)&BhS[buf][g * 512 + ls * 128 + lr * 8]; };
  auto LDBl = [&](int buf, int g) { return *(const bf16x8*)&BlS[buf][g * 512 + ls * 128 + lr * 8]; };

  stage_all(0, 0);
  asm volatile("s_waitcnt vmcnt(0)" ::: "memory");
  barrier_fenced();

#pragma unroll 1
  for (int t = 0; t < NTILES; ++t) {
    const int buf = t & 1, nb = buf ^ 1;
    const bool st = (t + 1 < NTILES);
    bf16x8 ah[4], al[4], bh[2], bl[2];

    // w0: Ah,Bh,Bl reads; issue slab t+1; 16 MFMA (ah.bh + ah.bl)
#pragma unroll
    for (int mt = 0; mt < 4; ++mt) ah[mt] = LDAh(buf, wm * MT + mt);
#pragma unroll
    for (int nt = 0; nt < 2; ++nt) bh[nt] = LDBh(buf, wn * NT + nt);
#pragma unroll
    for (int nt = 0; nt < 2; ++nt) bl[nt] = LDBl(buf, wn * NT + nt);
    if (st) stage_all(nb, t + 1);
    barrier_fenced();
    asm volatile("s_waitcnt lgkmcnt(0)" ::: "memory");
    __builtin_amdgcn_sched_barrier(0);
    __builtin_amdgcn_s_setprio(1);
#pragma unroll
    for (int mt = 0; mt < 4; ++mt)
#pragma unroll
      for (int nt = 0; nt < 2; ++nt)
        acc[mt][nt] = __builtin_amdgcn_mfma_f32_16x16x32_bf16(ah[mt], bh[nt], acc[mt][nt], 0, 0, 0);
#pragma unroll
    for (int mt = 0; mt < 4; ++mt)
#pragma unroll
      for (int nt = 0; nt < 2; ++nt)
        acc[mt][nt] = __builtin_amdgcn_mfma_f32_16x16x32_bf16(ah[mt], bl[nt], acc[mt][nt], 0, 0, 0);
    __builtin_amdgcn_s_setprio(0);
    __builtin_amdgcn_sched_barrier(0);

    // w1: Al reads; 8 MFMA (al.bh)
#pragma unroll
    for (int mt = 0; mt < 4; ++mt) al[mt] = LDAl(buf, wm * MT + mt);
    barrier_fenced();
    asm volatile("s_waitcnt lgkmcnt(0)" ::: "memory");
    __builtin_amdgcn_sched_barrier(0);
    __builtin_amdgcn_s_setprio(1);
#pragma unroll
    for (int mt = 0; mt < 4; ++mt)
#pragma unroll
      for (int nt = 0; nt < 2; ++nt)
        acc[mt][nt] = __builtin_amdgcn_mfma_f32_16x16x32_bf16(al[mt], bh[nt], acc[mt][nt], 0, 0, 0);
    __builtin_amdgcn_s_setprio(0);
    __builtin_amdgcn_sched_barrier(0);

    // boundary
    __builtin_amdgcn_sched_barrier(0);
    asm volatile("s_waitcnt vmcnt(0) lgkmcnt(0)" ::: "memory");
    barrier_fenced();
  }

  const int cm0 = bm + wm * 64;
  const int cn0 = bn + wn * 32;
#pragma unroll
  for (int mt = 0; mt < MT; ++mt)
#pragma unroll
    for (int nt = 0; nt < NT; ++nt) {
      const int col = cn0 + nt * 16 + lr;
      const int row0 = cm0 + mt * 16 + ls * 4;
#pragma unroll
      for (int r = 0; r < 4; ++r)
        C[(size_t)(row0 + r) * 1024 + col] = acc[mt][nt][r];
    }
}

// P = Pa + Pb; split hi/lo into Ph, Pl. Row per block.
__global__ __launch_bounds__(256)
void reduce_split(const float* __restrict__ Pa, const float* __restrict__ Pb,
                  unsigned short* __restrict__ Ph, unsigned short* __restrict__ Pl) {
  const size_t row = blockIdx.x;
  const int c4 = threadIdx.x;
  float4 a = ((const float4*)(Pa + row * 1024))[c4];
  float4 b = ((const float4*)(Pb + row * 1024))[c4];
  float s[4] = {a.x + b.x, a.y + b.y, a.z + b.z, a.w + b.w};
  u16x4 h, l;
#pragma unroll
  for (int i = 0; i < 4; ++i) {
    unsigned short hh = f2bf(s[i]);
    h[i] = hh;
    l[i] = f2bf(s[i] - bf2f(hh));
  }
  ((u16x4*)(Ph + row * 1024))[c4] = h;
  ((u16x4*)(Pl + row * 1024))[c4] = l;
}

// In-place row softmax, N=4096, one block per row, 16 floats/thread in regs.
__global__ __launch_bounds__(256)
void softmax_inplace(float* __restrict__ C, int N) {
  float4* r4 = (float4*)(C + (size_t)blockIdx.x * N);
  const int t = threadIdx.x;
  float4 v[4];
  float mx = -3.0e38f;
#pragma unroll
  for (int i = 0; i < 4; ++i) {
    v[i] = r4[t + i * 256];
    mx = fmaxf(mx, fmaxf(fmaxf(v[i].x, v[i].y), fmaxf(v[i].z, v[i].w)));
  }
#pragma unroll
  for (int o = 32; o; o >>= 1) mx = fmaxf(mx, __shfl_xor(mx, o, 64));
  __shared__ float smax[4], ssum[4];
  const int w = t >> 6;
  if ((t & 63) == 0) smax[w] = mx;
  __syncthreads();
  mx = fmaxf(fmaxf(smax[0], smax[1]), fmaxf(smax[2], smax[3]));
  float s = 0.f;
#pragma unroll
  for (int i = 0; i < 4; ++i) {
    v[i].x = __expf(v[i].x - mx);
    v[i].y = __expf(v[i].y - mx);
    v[i].z = __expf(v[i].z - mx);
    v[i].w = __expf(v[i].w - mx);
    s += (v[i].x + v[i].y) + (v[i].z + v[i].w);
  }
#pragma unroll
  for (int o = 32; o; o >>= 1) s += __shfl_xor(s, o, 64);
  if ((t & 63) == 0) ssum[w] = s;
  __syncthreads();
  const float inv = 1.0f / (ssum[0] + ssum[1] + ssum[2] + ssum[3]);
#pragma unroll
  for (int i = 0; i < 4; ++i) {
    v[i].x *= inv; v[i].y *= inv; v[i].z *= inv; v[i].w *= inv;
    r4[t + i * 256] = v[i];
  }
}

extern "C" void kernel_launch(void* const* d_in, const int* in_sizes, int n_in,
                              void* d_out, int out_size, void* d_ws, size_t ws_size,
                              hipStream_t stream) {
  const float* out_state = (const float*)d_in[0];  // [4096,1024]
  const float* history   = (const float*)d_in[1];  // [4096,1024]
  const float* W         = (const float*)d_in[2];  // [1024,1024]
  float* out = (float*)d_out;                      // [4096,4096]

  unsigned short* Hh = (unsigned short*)d_ws;                 // 4096x1024 each
  unsigned short* Hl = Hh + (size_t)4096 * 1024;
  unsigned short* Wh = Hl + (size_t)4096 * 1024;              // 1024x1024
  unsigned short* Wl = Wh + (size_t)1024 * 1024;
  unsigned short* Ah = Wl + (size_t)1024 * 1024;              // 4096x1024
  unsigned short* Al = Ah + (size_t)4096 * 1024;
  unsigned short* Ph = Al + (size_t)4096 * 1024;              // 4096x1024
  unsigned short* Pl = Ph + (size_t)4096 * 1024;
  float* P32 = (float*)(Pl + (size_t)4096 * 1024);            // 2 x 4096x1024 fp32

  split_all<<<9216, 256, 0, stream>>>(history, W, out_state, Hh, Hl, Wh, Wl, Ah, Al);

  // stage-1: split-K=2 proj (R17-exact). 512 blocks, 2 blocks/CU.
  gemm_p<<<512, 512, 0, stream>>>(Hh, Hl, Wh, Wl, P32);
  reduce_split<<<4096, 256, 0, stream>>>(P32, P32 + (size_t)4096 * 1024, Ph, Pl);

  // stage-2: energies, 32x32x16 MFMA. 256 blocks.
  gemm_e<<<256, 512, 0, stream>>>(Ah, Al, Ph, Pl, out);

  softmax_inplace<<<4096, 256, 0, stream>>>(out, 4096);
}